// Round 1
// baseline (314.504 us; speedup 1.0000x reference)
//
#include <hip/hip_runtime.h>

typedef __bf16 bf16;
typedef __bf16 bf16_4 __attribute__((ext_vector_type(4)));
typedef __bf16 bf16_8 __attribute__((ext_vector_type(8)));
typedef float f32_4 __attribute__((ext_vector_type(4)));

#define LDS_PITCH 40   // 32 + 8 pad, keeps 16B alignment (80B rows), breaks pow2 strides

// ---------------- f32 -> bf16 convert (vectorized x4) ----------------
__global__ __launch_bounds__(256) void convert_f32_bf16(const float* __restrict__ src,
                                                        bf16* __restrict__ dst, int n4) {
    int i = blockIdx.x * 256 + threadIdx.x;
    if (i < n4) {
        float4 v = reinterpret_cast<const float4*>(src)[i];
        bf16_4 o;
        o.x = (bf16)v.x; o.y = (bf16)v.y; o.z = (bf16)v.z; o.w = (bf16)v.w;
        reinterpret_cast<bf16_4*>(dst)[i] = o;
    }
}

// ---------------- generic C = A * W^T (+bias) bf16 MFMA GEMM ----------------
// A: (M x K) row-major bf16, lda; W: (N x K) row-major bf16, ldw.
// MODE 0: bf16 out row-major (ld=N), +bias
// MODE 1: f32 out row-major (ld=N), +bias
// MODE 2: f32 out row-major, val = acc*scale - slopes[1]*|m-n|   (scores+ALiBi)
// MODE 3: bf16 out scattered to flat attn layout: (n>>6)*131072 + m*64 + (n&63)
template<int MODE>
__global__ __launch_bounds__(256) void gemm_bt(
    const bf16* __restrict__ A, int lda, long long aBatch,
    const bf16* __restrict__ W, int ldw, long long wBatch,
    const float* __restrict__ bias,
    void* __restrict__ outp, long long outBatch,
    int N, int K, float scale, const float* __restrict__ slopes)
{
    __shared__ alignas(16) bf16 As[128 * LDS_PITCH];
    __shared__ alignas(16) bf16 Bs[128 * LDS_PITCH];

    const int tid  = threadIdx.x;
    const int lane = tid & 63;
    const int wave = tid >> 6;
    const int wm   = (wave >> 1) * 64;
    const int wn   = (wave & 1) * 64;
    const int l15  = lane & 15;
    const int quad = lane >> 4;
    const int m0   = blockIdx.y * 128;
    const int n0   = blockIdx.x * 128;
    const int z    = blockIdx.z;

    const bf16* Ab = A + (long long)z * aBatch;
    const bf16* Wb = W + (long long)z * wBatch;

    const int r  = tid >> 2;         // 0..63
    const int c8 = (tid & 3) * 8;    // 0,8,16,24

    f32_4 acc[4][4];
#pragma unroll
    for (int i = 0; i < 4; i++)
#pragma unroll
        for (int j = 0; j < 4; j++) acc[i][j] = (f32_4)(0.0f);

    for (int k0 = 0; k0 < K; k0 += 32) {
        __syncthreads();
        *reinterpret_cast<float4*>(&As[r * LDS_PITCH + c8]) =
            *reinterpret_cast<const float4*>(&Ab[(long long)(m0 + r) * lda + k0 + c8]);
        *reinterpret_cast<float4*>(&As[(r + 64) * LDS_PITCH + c8]) =
            *reinterpret_cast<const float4*>(&Ab[(long long)(m0 + r + 64) * lda + k0 + c8]);
        *reinterpret_cast<float4*>(&Bs[r * LDS_PITCH + c8]) =
            *reinterpret_cast<const float4*>(&Wb[(long long)(n0 + r) * ldw + k0 + c8]);
        *reinterpret_cast<float4*>(&Bs[(r + 64) * LDS_PITCH + c8]) =
            *reinterpret_cast<const float4*>(&Wb[(long long)(n0 + r + 64) * ldw + k0 + c8]);
        __syncthreads();

        bf16_8 af[4], bfr[4];
#pragma unroll
        for (int t = 0; t < 4; t++) {
            af[t]  = *reinterpret_cast<const bf16_8*>(&As[(wm + t * 16 + l15) * LDS_PITCH + quad * 8]);
            bfr[t] = *reinterpret_cast<const bf16_8*>(&Bs[(wn + t * 16 + l15) * LDS_PITCH + quad * 8]);
        }
#pragma unroll
        for (int i = 0; i < 4; i++)
#pragma unroll
            for (int j = 0; j < 4; j++)
                acc[i][j] = __builtin_amdgcn_mfma_f32_16x16x32_bf16(af[i], bfr[j], acc[i][j], 0, 0, 0);
    }

    const float slope = (MODE == 2) ? slopes[1] : 0.0f;

#pragma unroll
    for (int i = 0; i < 4; i++) {
#pragma unroll
        for (int j = 0; j < 4; j++) {
#pragma unroll
            for (int rg = 0; rg < 4; rg++) {
                int m = m0 + wm + i * 16 + quad * 4 + rg;
                int n = n0 + wn + j * 16 + l15;
                float v = acc[i][j][rg];
                if (MODE == 0) {
                    if (bias) v += bias[n];
                    ((bf16*)outp)[(long long)z * outBatch + (long long)m * N + n] = (bf16)v;
                } else if (MODE == 1) {
                    if (bias) v += bias[n];
                    ((float*)outp)[(long long)z * outBatch + (long long)m * N + n] = v;
                } else if (MODE == 2) {
                    float d = fabsf((float)(m - n));
                    v = v * scale - slope * d;
                    ((float*)outp)[(long long)z * outBatch + (long long)m * N + n] = v;
                } else {
                    long long off = (long long)z * outBatch +
                                    ((long long)(n >> 6)) * 131072LL + (long long)m * 64 + (n & 63);
                    ((bf16*)outp)[off] = (bf16)v;
                }
            }
        }
    }
}

// ---------------- V transpose: v[b](flat heads: h,k,d) -> vt[b][h*64+d][k] ----------------
__global__ __launch_bounds__(256) void transpose_v(const unsigned short* __restrict__ v,
                                                   unsigned short* __restrict__ vt) {
    __shared__ unsigned short tile[64 * 66];
    const int t  = threadIdx.x;
    const int k0 = blockIdx.x * 64;
    const int h  = blockIdx.y;
    const int b  = blockIdx.z;
    const unsigned short* src = v + (long long)b * 2097152LL + (long long)h * 131072LL;
#pragma unroll
    for (int p = 0; p < 8; p++) {
        int idx = t + p * 256;       // 0..2047
        int k   = idx >> 5;          // 0..63
        int dc  = idx & 31;          // d pair
        ushort2 u = *reinterpret_cast<const ushort2*>(&src[(long long)(k0 + k) * 64 + dc * 2]);
        tile[(dc * 2) * 66 + k]     = u.x;
        tile[(dc * 2 + 1) * 66 + k] = u.y;
    }
    __syncthreads();
    unsigned short* dst = vt + (long long)b * 2097152LL + (long long)h * 64 * 2048LL + k0;
#pragma unroll
    for (int p = 0; p < 8; p++) {
        int idx = t + p * 256;
        int d   = idx >> 5;
        int kc  = idx & 31;
        ushort2 u;
        u.x = tile[d * 66 + kc * 2];
        u.y = tile[d * 66 + kc * 2 + 1];
        *reinterpret_cast<ushort2*>(&dst[(long long)d * 2048 + kc * 2]) = u;
    }
}

// ---------------- row softmax: 2048 cols; write f32 probs + bf16 probs ----------------
__global__ __launch_bounds__(256) void softmax_row(const float* __restrict__ scores,
                                                   float* __restrict__ pf,
                                                   bf16* __restrict__ pb) {
    __shared__ float redmax[4];
    __shared__ float redsum[4];
    const long long row = blockIdx.x;
    const float* src = scores + row * 2048LL;
    const int t = threadIdx.x;

    float4 v0 = reinterpret_cast<const float4*>(src)[t];
    float4 v1 = reinterpret_cast<const float4*>(src)[t + 256];

    float mx = fmaxf(fmaxf(v0.x, v0.y), fmaxf(v0.z, v0.w));
    mx = fmaxf(mx, fmaxf(fmaxf(v1.x, v1.y), fmaxf(v1.z, v1.w)));
#pragma unroll
    for (int o = 32; o > 0; o >>= 1) mx = fmaxf(mx, __shfl_down(mx, o, 64));
    if ((t & 63) == 0) redmax[t >> 6] = mx;
    __syncthreads();
    mx = fmaxf(fmaxf(redmax[0], redmax[1]), fmaxf(redmax[2], redmax[3]));

    float4 e0, e1;
    e0.x = expf(v0.x - mx); e0.y = expf(v0.y - mx); e0.z = expf(v0.z - mx); e0.w = expf(v0.w - mx);
    e1.x = expf(v1.x - mx); e1.y = expf(v1.y - mx); e1.z = expf(v1.z - mx); e1.w = expf(v1.w - mx);
    float s = e0.x + e0.y + e0.z + e0.w + e1.x + e1.y + e1.z + e1.w;
#pragma unroll
    for (int o = 32; o > 0; o >>= 1) s += __shfl_down(s, o, 64);
    if ((t & 63) == 0) redsum[t >> 6] = s;
    __syncthreads();
    s = redsum[0] + redsum[1] + redsum[2] + redsum[3];
    float inv = 1.0f / s;

    e0.x *= inv; e0.y *= inv; e0.z *= inv; e0.w *= inv;
    e1.x *= inv; e1.y *= inv; e1.z *= inv; e1.w *= inv;

    reinterpret_cast<float4*>(pf + row * 2048LL)[t]       = e0;
    reinterpret_cast<float4*>(pf + row * 2048LL)[t + 256] = e1;

    bf16_4 b0, b1;
    b0.x = (bf16)e0.x; b0.y = (bf16)e0.y; b0.z = (bf16)e0.z; b0.w = (bf16)e0.w;
    b1.x = (bf16)e1.x; b1.y = (bf16)e1.y; b1.z = (bf16)e1.z; b1.w = (bf16)e1.w;
    reinterpret_cast<bf16_4*>(pb + row * 2048LL)[t]       = b0;
    reinterpret_cast<bf16_4*>(pb + row * 2048LL)[t + 256] = b1;
}

// ---------------- launcher ----------------
extern "C" void kernel_launch(void* const* d_in, const int* in_sizes, int n_in,
                              void* d_out, int out_size, void* d_ws, size_t ws_size,
                              hipStream_t stream) {
    const float* x      = (const float*)d_in[0];
    const float* Wq     = (const float*)d_in[1];
    const float* bq     = (const float*)d_in[2];
    const float* Wk     = (const float*)d_in[3];
    const float* bk     = (const float*)d_in[4];
    const float* Wv     = (const float*)d_in[5];
    const float* bv     = (const float*)d_in[6];
    const float* Wo     = (const float*)d_in[7];
    const float* bo     = (const float*)d_in[8];
    const float* slopes = (const float*)d_in[9];

    // B=2, S=2048, E=1024, H=16, hd=64
    char* w = (char*)d_ws;
    bf16* x_bf  = (bf16*)w;               w += 4096LL * 1024 * 2;   // 8 MB
    bf16* wq_bf = (bf16*)w;               w += 1024LL * 1024 * 2;
    bf16* wk_bf = (bf16*)w;               w += 1024LL * 1024 * 2;
    bf16* wv_bf = (bf16*)w;               w += 1024LL * 1024 * 2;
    bf16* wo_bf = (bf16*)w;               w += 1024LL * 1024 * 2;
    bf16* qh1   = (bf16*)w;               w += 2LL * 128 * 1024 * 2; // head1 Q: (b,2048,64)
    bf16* kh1   = (bf16*)w;               w += 2LL * 128 * 1024 * 2;
    bf16* v_bf  = (bf16*)w;               w += 4096LL * 1024 * 2;
    bf16* vt    = (bf16*)w;               w += 2LL * 1024 * 2048 * 2;
    float* sc   = (float*)w;              w += 2LL * 2048 * 2048 * 4; // 33.5 MB
    bf16* pb    = (bf16*)w;               w += 2LL * 2048 * 2048 * 2; // 16.8 MB
    bf16* attn  = (bf16*)w;               w += 4096LL * 1024 * 2;

    float* out_f   = (float*)d_out;               // (B,S,E) = 4194304 floats
    float* probs_f = (float*)d_out + 4194304LL;   // (B,1,S,S) = 8388608 floats

    // 1) converts
    convert_f32_bf16<<<4096, 256, 0, stream>>>(x,  x_bf,  1048576);
    convert_f32_bf16<<<1024, 256, 0, stream>>>(Wq, wq_bf, 262144);
    convert_f32_bf16<<<1024, 256, 0, stream>>>(Wk, wk_bf, 262144);
    convert_f32_bf16<<<1024, 256, 0, stream>>>(Wv, wv_bf, 262144);
    convert_f32_bf16<<<1024, 256, 0, stream>>>(Wo, wo_bf, 262144);

    // 2) Q head-1 proj: rows 128..255 of each batch of x @ Wq^T -> qh1 (b,128,1024)
    gemm_bt<0><<<dim3(8, 1, 2), 256, 0, stream>>>(
        x_bf + 128LL * 1024, 1024, 2048LL * 1024,
        wq_bf, 1024, 0LL, bq, qh1, 128LL * 1024, 1024, 1024, 1.0f, nullptr);
    // 3) K head-1 proj
    gemm_bt<0><<<dim3(8, 1, 2), 256, 0, stream>>>(
        x_bf + 128LL * 1024, 1024, 2048LL * 1024,
        wk_bf, 1024, 0LL, bk, kh1, 128LL * 1024, 1024, 1024, 1.0f, nullptr);
    // 4) V proj (full): (4096x1024) bf16
    gemm_bt<0><<<dim3(8, 32, 1), 256, 0, stream>>>(
        x_bf, 1024, 0LL, wv_bf, 1024, 0LL, bv, v_bf, 0LL, 1024, 1024, 1.0f, nullptr);

    // 5) V transpose to vt[b][h*64+d][k]
    transpose_v<<<dim3(32, 16, 2), 256, 0, stream>>>((const unsigned short*)v_bf,
                                                     (unsigned short*)vt);

    // 6) scores (head 1): per b (2048x2048) = qh1 @ kh1^T * 0.125 - slope1*|q-k|
    gemm_bt<2><<<dim3(16, 16, 2), 256, 0, stream>>>(
        qh1, 64, 131072LL, kh1, 64, 131072LL, nullptr,
        sc, 2048LL * 2048, 2048, 64, 0.125f, slopes);

    // 7) softmax rows -> probs f32 (d_out) + bf16 (ws)
    softmax_row<<<4096, 256, 0, stream>>>(sc, probs_f, pb);

    // 8) PV: per b (2048x1024) = P @ Vcat, scatter to flat attn layout (bf16)
    gemm_bt<3><<<dim3(8, 16, 2), 256, 0, stream>>>(
        pb, 2048, 2048LL * 2048, vt, 2048, 1024LL * 2048, nullptr,
        attn, 2048LL * 1024, 1024, 2048, 1.0f, nullptr);

    // 9) out proj: (4096x1024) f32 = attn @ Wo^T + bo  -> d_out
    gemm_bt<1><<<dim3(8, 32, 1), 256, 0, stream>>>(
        attn, 1024, 0LL, wo_bf, 1024, 0LL, bo,
        out_f, 0LL, 1024, 1024, 1.0f, nullptr);
}

// Round 4
// 217.881 us; speedup vs baseline: 1.4435x; 1.4435x over previous
//
#include <hip/hip_runtime.h>

typedef __bf16 bf16;
typedef __bf16 bf16_4 __attribute__((ext_vector_type(4)));
typedef __bf16 bf16_8 __attribute__((ext_vector_type(8)));
typedef float f32_4 __attribute__((ext_vector_type(4)));

// async global->LDS, 16B per lane; LDS dest must be wave-uniform base + lane*16
#define GLDS16(g, l) \
  __builtin_amdgcn_global_load_lds((const __attribute__((address_space(1))) unsigned int*)(g), \
                                   (__attribute__((address_space(3))) unsigned int*)(l), 16, 0, 0)

// ---------------- fused f32 -> bf16 convert for x + 4 weights ----------------
__global__ __launch_bounds__(256) void convert_all(
    const float* __restrict__ x, const float* __restrict__ wq, const float* __restrict__ wk,
    const float* __restrict__ wv, const float* __restrict__ wo,
    bf16* __restrict__ xb, bf16* __restrict__ wqb, bf16* __restrict__ wkb,
    bf16* __restrict__ wvb, bf16* __restrict__ wob)
{
    int i = blockIdx.x * 256 + threadIdx.x;     // 0 .. 2097151 float4 units
    const float* s; bf16* d; int off;
    if (i < 1048576) { s = x; d = xb; off = i; }
    else {
        int j = i - 1048576;
        int sel = j >> 18;                      // 0..3 (262144 float4 per weight)
        off = j & 262143;
        s = (sel == 0) ? wq : (sel == 1) ? wk : (sel == 2) ? wv : wo;
        d = (sel == 0) ? wqb : (sel == 1) ? wkb : (sel == 2) ? wvb : wob;
    }
    float4 v = reinterpret_cast<const float4*>(s)[off];
    bf16_4 o; o.x = (bf16)v.x; o.y = (bf16)v.y; o.z = (bf16)v.z; o.w = (bf16)v.w;
    reinterpret_cast<bf16_4*>(d)[off] = o;
}

// ---------------- C = A * W^T (+bias) bf16 MFMA GEMM, global_load_lds staging --------
// BK = 64 (128B LDS rows). XOR swizzle: 16B chunk q of row r stored at slot q^(r&7).
// BM = 128: 4 waves 2x2, each 64x64 (acc 4x4).  BM = 64: waves split N, each 64x32 (acc 4x2).
// MODE 0: bf16 out row-major (+bias)
// MODE 1: f32 out row-major (+bias)
// MODE 2: f32 out, v*scale - slopes[1]*|m-n|  (scores + ALiBi, head 1)
// MODE 3: bf16 out scattered to flat attn layout: (n>>6)*131072 + m*64 + (n&63)
// MODE 5: like 0, but z selects {W,bias,out} (z<2) vs {W2,bias2,out2} (z>=2), batch = z&1
template<int BM, int MODE>
__global__ __launch_bounds__(256) void gemm_glds(
    const bf16* __restrict__ A, int lda, long long aBatch,
    const bf16* __restrict__ W, int ldw, long long wBatch,
    const float* __restrict__ bias,
    void* __restrict__ outp, long long outBatch,
    int N, int K, float scale, const float* __restrict__ slopes,
    const bf16* __restrict__ W2, const float* __restrict__ bias2, void* __restrict__ out2)
{
    constexpr int CA = BM * 8;                   // A 16B-chunks per tile
    constexpr int NJ = (BM == 128) ? 4 : 2;
    __shared__ alignas(16) bf16 As[BM * 64];
    __shared__ alignas(16) bf16 Bs[128 * 64];

    const int tid  = threadIdx.x;
    const int lane = tid & 63;
    const int wave = tid >> 6;
    const int l15  = lane & 15;
    const int quad = lane >> 4;
    const int m0   = blockIdx.y * BM;
    const int n0   = blockIdx.x * 128;
    const int z    = blockIdx.z;

    const int WM = (BM == 128) ? (wave >> 1) * 64 : 0;
    const int WN = (BM == 128) ? (wave & 1) * 64 : wave * 32;

    const bf16* Ab; const bf16* Wb; const float* bvec; void* op;
    if (MODE == 5) {
        int sel = z >> 1;
        Ab   = A + (long long)(z & 1) * aBatch;
        Wb   = sel ? W2 : W;
        bvec = sel ? bias2 : bias;
        op   = sel ? out2 : outp;
    } else {
        Ab = A + (long long)z * aBatch; Wb = W + (long long)z * wBatch;
        bvec = bias; op = outp;
    }

    f32_4 acc[4][NJ];
#pragma unroll
    for (int i = 0; i < 4; i++)
#pragma unroll
        for (int j = 0; j < NJ; j++) acc[i][j] = (f32_4)(0.0f);

    for (int k0 = 0; k0 < K; k0 += 64) {
        // ---- stage A tile (BM x 64) ----
#pragma unroll
        for (int it = 0; it < CA / 256; ++it) {
            int p = wave * (CA / 4) + it * 64 + lane;
            int r = p >> 3;
            int q = (p & 7) ^ (r & 7);
            GLDS16(Ab + (long long)(m0 + r) * lda + k0 + q * 8, As + p * 8);
        }
        // ---- stage B tile (128 x 64) ----
#pragma unroll
        for (int it = 0; it < 4; ++it) {
            int p = wave * 256 + it * 64 + lane;
            int r = p >> 3;
            int q = (p & 7) ^ (r & 7);
            GLDS16(Wb + (long long)(n0 + r) * ldw + k0 + q * 8, Bs + p * 8);
        }
        __syncthreads();   // drains vmcnt(0) for the glds queue

#pragma unroll
        for (int kh = 0; kh < 2; ++kh) {
            bf16_8 af[4], bfr[NJ];
#pragma unroll
            for (int t = 0; t < 4; ++t) {
                int r = WM + t * 16 + l15;
                int q = (kh * 4 + quad) ^ (r & 7);
                af[t] = *reinterpret_cast<const bf16_8*>(&As[r * 64 + q * 8]);
            }
#pragma unroll
            for (int j = 0; j < NJ; ++j) {
                int r = WN + j * 16 + l15;
                int q = (kh * 4 + quad) ^ (r & 7);
                bfr[j] = *reinterpret_cast<const bf16_8*>(&Bs[r * 64 + q * 8]);
            }
#pragma unroll
            for (int i = 0; i < 4; ++i)
#pragma unroll
                for (int j = 0; j < NJ; ++j)
                    acc[i][j] = __builtin_amdgcn_mfma_f32_16x16x32_bf16(af[i], bfr[j], acc[i][j], 0, 0, 0);
        }
        __syncthreads();   // protect LDS before next iteration's staging
    }

    long long obase = (long long)((MODE == 5) ? (z & 1) : z) * outBatch;
    const float slope = (MODE == 2) ? slopes[1] : 0.0f;

#pragma unroll
    for (int i = 0; i < 4; i++) {
#pragma unroll
        for (int j = 0; j < NJ; j++) {
#pragma unroll
            for (int rg = 0; rg < 4; rg++) {
                int m = m0 + WM + i * 16 + quad * 4 + rg;
                int n = n0 + WN + j * 16 + l15;
                float v = acc[i][j][rg];
                if (MODE == 0 || MODE == 5) {
                    if (bvec) v += bvec[n];
                    ((bf16*)op)[obase + (long long)m * N + n] = (bf16)v;
                } else if (MODE == 1) {
                    if (bvec) v += bvec[n];
                    ((float*)op)[obase + (long long)m * N + n] = v;
                } else if (MODE == 2) {
                    v = v * scale - slope * fabsf((float)(m - n));
                    ((float*)op)[obase + (long long)m * N + n] = v;
                } else {  // MODE 3: scatter PV(m,n) into flat attn layout
                    long long off = obase +
                                    ((long long)(n >> 6)) * 131072LL + (long long)m * 64 + (n & 63);
                    ((bf16*)op)[off] = (bf16)v;
                }
            }
        }
    }
}

// ---------------- V transpose: v[b](flat heads: h,k,d) -> vt[b][h*64+d][k] ----------------
__global__ __launch_bounds__(256) void transpose_v(const unsigned short* __restrict__ v,
                                                   unsigned short* __restrict__ vt) {
    __shared__ unsigned short tile[64 * 66];
    const int t  = threadIdx.x;
    const int k0 = blockIdx.x * 64;
    const int h  = blockIdx.y;
    const int b  = blockIdx.z;
    const unsigned short* src = v + (long long)b * 2097152LL + (long long)h * 131072LL;
#pragma unroll
    for (int p = 0; p < 8; p++) {
        int idx = t + p * 256;       // 0..2047
        int k   = idx >> 5;          // 0..63
        int dc  = idx & 31;          // d pair
        ushort2 u = *reinterpret_cast<const ushort2*>(&src[(long long)(k0 + k) * 64 + dc * 2]);
        tile[(dc * 2) * 66 + k]     = u.x;
        tile[(dc * 2 + 1) * 66 + k] = u.y;
    }
    __syncthreads();
    unsigned short* dst = vt + (long long)b * 2097152LL + (long long)h * 64 * 2048LL + k0;
#pragma unroll
    for (int p = 0; p < 8; p++) {
        int idx = t + p * 256;
        int d   = idx >> 5;
        int kc  = idx & 31;
        ushort2 u;
        u.x = tile[d * 66 + kc * 2];
        u.y = tile[d * 66 + kc * 2 + 1];
        *reinterpret_cast<ushort2*>(&dst[(long long)d * 2048 + kc * 2]) = u;
    }
}

// ---------------- row softmax: 2048 cols; write f32 probs (d_out) + bf16 probs ----------------
__global__ __launch_bounds__(256) void softmax_row(const float* __restrict__ scores,
                                                   float* __restrict__ pf,
                                                   bf16* __restrict__ pb) {
    __shared__ float redmax[4];
    __shared__ float redsum[4];
    const long long row = blockIdx.x;
    const float* src = scores + row * 2048LL;
    const int t = threadIdx.x;

    float4 v0 = reinterpret_cast<const float4*>(src)[t];
    float4 v1 = reinterpret_cast<const float4*>(src)[t + 256];

    float mx = fmaxf(fmaxf(v0.x, v0.y), fmaxf(v0.z, v0.w));
    mx = fmaxf(mx, fmaxf(fmaxf(v1.x, v1.y), fmaxf(v1.z, v1.w)));
#pragma unroll
    for (int o = 32; o > 0; o >>= 1) mx = fmaxf(mx, __shfl_down(mx, o, 64));
    if ((t & 63) == 0) redmax[t >> 6] = mx;
    __syncthreads();
    mx = fmaxf(fmaxf(redmax[0], redmax[1]), fmaxf(redmax[2], redmax[3]));

    float4 e0, e1;
    e0.x = expf(v0.x - mx); e0.y = expf(v0.y - mx); e0.z = expf(v0.z - mx); e0.w = expf(v0.w - mx);
    e1.x = expf(v1.x - mx); e1.y = expf(v1.y - mx); e1.z = expf(v1.z - mx); e1.w = expf(v1.w - mx);
    float s = e0.x + e0.y + e0.z + e0.w + e1.x + e1.y + e1.z + e1.w;
#pragma unroll
    for (int o = 32; o > 0; o >>= 1) s += __shfl_down(s, o, 64);
    if ((t & 63) == 0) redsum[t >> 6] = s;
    __syncthreads();
    s = redsum[0] + redsum[1] + redsum[2] + redsum[3];
    float inv = 1.0f / s;

    e0.x *= inv; e0.y *= inv; e0.z *= inv; e0.w *= inv;
    e1.x *= inv; e1.y *= inv; e1.z *= inv; e1.w *= inv;

    reinterpret_cast<float4*>(pf + row * 2048LL)[t]       = e0;
    reinterpret_cast<float4*>(pf + row * 2048LL)[t + 256] = e1;

    bf16_4 b0, b1;
    b0.x = (bf16)e0.x; b0.y = (bf16)e0.y; b0.z = (bf16)e0.z; b0.w = (bf16)e0.w;
    b1.x = (bf16)e1.x; b1.y = (bf16)e1.y; b1.z = (bf16)e1.z; b1.w = (bf16)e1.w;
    reinterpret_cast<bf16_4*>(pb + row * 2048LL)[t]       = b0;
    reinterpret_cast<bf16_4*>(pb + row * 2048LL)[t + 256] = b1;
}

// ---------------- launcher ----------------
extern "C" void kernel_launch(void* const* d_in, const int* in_sizes, int n_in,
                              void* d_out, int out_size, void* d_ws, size_t ws_size,
                              hipStream_t stream) {
    const float* x      = (const float*)d_in[0];
    const float* Wq     = (const float*)d_in[1];
    const float* bq     = (const float*)d_in[2];
    const float* Wk     = (const float*)d_in[3];
    const float* bk     = (const float*)d_in[4];
    const float* Wv     = (const float*)d_in[5];
    const float* bv     = (const float*)d_in[6];
    const float* Wo     = (const float*)d_in[7];
    const float* bo     = (const float*)d_in[8];
    const float* slopes = (const float*)d_in[9];

    // B=2, S=2048, E=1024, H=16, hd=64
    char* w = (char*)d_ws;
    bf16* x_bf  = (bf16*)w;  w += 4096LL * 1024 * 2;      // 8.4 MB
    bf16* wq_bf = (bf16*)w;  w += 1024LL * 1024 * 2;
    bf16* wk_bf = (bf16*)w;  w += 1024LL * 1024 * 2;
    bf16* wv_bf = (bf16*)w;  w += 1024LL * 1024 * 2;
    bf16* wo_bf = (bf16*)w;  w += 1024LL * 1024 * 2;
    bf16* qh1   = (bf16*)w;  w += 2LL * 131072 * 2;       // head-1 Q: per b (2048,64) flat
    bf16* kh1   = (bf16*)w;  w += 2LL * 131072 * 2;
    bf16* v_bf  = (bf16*)w;  w += 4096LL * 1024 * 2;      // V proj, row-major (b*2048+s, 1024)
    bf16* vt    = (bf16*)w;  w += 2LL * 1024 * 2048 * 2;  // vt[b][h*64+d][k]
    bf16* attn  = (bf16*)w;  w += 4096LL * 1024 * 2;      // flat attn layout
    float* sc   = (float*)w; w += 2LL * 2048 * 2048 * 4;  // 33.5 MB
    bf16* pb    = (bf16*)w;  w += 2LL * 2048 * 2048 * 2;  // 16.8 MB

    float* out_f   = (float*)d_out;                // (B,S,E)
    float* probs_f = (float*)d_out + 4194304LL;    // (B,1,S,S)

    // 1) all f32->bf16 converts in one launch
    convert_all<<<8192, 256, 0, stream>>>(x, Wq, Wk, Wv, Wo, x_bf, wq_bf, wk_bf, wv_bf, wo_bf);

    // 2) Q & K head-1 projections in one launch: rows 128..255 per batch of x @ {Wq,Wk}^T
    gemm_glds<64, 5><<<dim3(8, 2, 4), 256, 0, stream>>>(
        x_bf + 128LL * 1024, 1024, 2048LL * 1024,
        wq_bf, 1024, 0LL, bq, qh1, 131072LL, 1024, 1024, 1.0f, nullptr,
        wk_bf, bk, kh1);

    // 3) V projection (full): (4096 x 1024) bf16 row-major
    gemm_glds<64, 0><<<dim3(8, 64, 1), 256, 0, stream>>>(
        x_bf, 1024, 0LL, wv_bf, 1024, 0LL, bv, v_bf, 0LL, 1024, 1024, 1.0f, nullptr,
        nullptr, nullptr, nullptr);

    // 4) V transpose to vt[b][h*64+d][k]
    transpose_v<<<dim3(32, 16, 2), 256, 0, stream>>>((const unsigned short*)v_bf,
                                                     (unsigned short*)vt);

    // 5) scores head-1: per b (2048x2048) = qh1 @ kh1^T * 0.125 - slope1*|m-n|
    gemm_glds<128, 2><<<dim3(16, 16, 2), 256, 0, stream>>>(
        qh1, 64, 131072LL, kh1, 64, 131072LL, nullptr,
        sc, 4194304LL, 2048, 64, 0.125f, slopes,
        nullptr, nullptr, nullptr);

    // 6) softmax rows -> probs f32 (d_out) + bf16 (ws)
    softmax_row<<<4096, 256, 0, stream>>>(sc, probs_f, pb);

    // 7) PV: per b (2048x1024) = P @ vt^T, scatter to flat attn layout (bf16)
    gemm_glds<64, 3><<<dim3(8, 32, 2), 256, 0, stream>>>(
        pb, 2048, 4194304LL, vt, 2048, 2097152LL, nullptr,
        attn, 2097152LL, 1024, 2048, 1.0f, nullptr,
        nullptr, nullptr, nullptr);

    // 8) out proj: (4096x1024) f32 = attn @ Wo^T + bo -> d_out   (K=1024!)
    gemm_glds<64, 1><<<dim3(8, 64, 1), 256, 0, stream>>>(
        attn, 1024, 0LL, wo_bf, 1024, 0LL, bo,
        out_f, 0LL, 1024, 1024, 1.0f, nullptr,
        nullptr, nullptr, nullptr);
}